// Round 12
// baseline (223.973 us; speedup 1.0000x reference)
//
#include <hip/hip_runtime.h>

// ---------------- problem constants ----------------
#define BATCH   8
#define LSEQ    1048576          // 1<<20
#define KCONV   500
#define TWIN    2097             // (L-K)/K + 1
#define MROWS   16776            // BATCH*TWIN
#define KDIM    4000             // KCONV * C_IN
#define NDIM    256              // 2 * C_OUT
#define COUT    128
#define VOCAB   257
#define VOCABP  256              // padding row of emb (zeros)

#define BMR     96               // m-rows per block (6 x 16): 2 row-groups x 3 tiles
#define NTILE   175              // ceil(MROWS/96): fits 256 CUs, 1 block/CU
#define SLABP   20               // positions per slab = 160 k = 5 BK32 iters
#define NSLAB   25
#define NG      125              // total BK32 iterations
#define PLANE   (NDIM * 32)      // 8192 shorts per g-plane of Wtf
#define AROWSH  168              // padded shorts per A-slab row (160 + 8)
#define STAGEN  (BMR * SLABP)    // 1920 gathers per slab

// ---------------- ws layout (bytes) ----------------
#define WTF_OFF   0ull
#define WTF_BYTES ((size_t)NG * PLANE * 2)                  // 2,048,000
#define POOL_OFF  (WTF_OFF + WTF_BYTES)                     // 1024 floats
#define CNT_OFF   (POOL_OFF + 4096)                         // 1 int

typedef __attribute__((ext_vector_type(8))) __bf16 bf16x8;
typedef __attribute__((ext_vector_type(4))) float  floatx4;

__device__ inline unsigned short f2bf(float f) {
    union { float f; unsigned u; } c; c.f = f;
    return (unsigned short)((c.u + 0x7FFFu + ((c.u >> 16) & 1u)) >> 16);
}
__device__ inline unsigned pack2(float lo, float hi) {
    return (unsigned)f2bf(lo) | ((unsigned)f2bf(hi) << 16);
}

// barrier that waits ONLY for LDS ops — leaves global (B/x prefetch) loads in flight
#define LDS_BARRIER() asm volatile("s_waitcnt lgkmcnt(0)\n\ts_barrier" ::: "memory")

// ---------------- kernel 1: frag-major weights + zero pool/counter ----------------
// Wtf[g][n][kk] = w_n[e=(g*32+kk)&7][p=(g*32+kk)>>3]
__global__ __launch_bounds__(256) void wprep_kernel(const float* __restrict__ w1,
                                                    const float* __restrict__ w2,
                                                    unsigned short* __restrict__ Wtf,
                                                    float* __restrict__ pool,
                                                    int* __restrict__ cnt) {
    const int n   = blockIdx.x;                        // 0..255
    const int tid = threadIdx.x;
    __shared__ float tile[KDIM];                       // 16 KB
    const float* src = (n < COUT) ? (w1 + (size_t)n * KDIM)
                                  : (w2 + (size_t)(n - COUT) * KDIM);
    for (int i = tid; i < KDIM; i += 256) tile[i] = src[i];
    __syncthreads();
    for (int i = tid; i < KDIM; i += 256) {
        int g = i >> 5, kk = i & 31;
        Wtf[(size_t)g * PLANE + n * 32 + kk] = f2bf(tile[(i & 7) * KCONV + (i >> 3)]);
    }
    if (n == 0) {
        if (tid < 256) ((float4*)pool)[tid] = float4{0.f, 0.f, 0.f, 0.f};
        if (tid == 0) *cnt = 0;
    }
}

// ---------------- kernel 2 ----------------
// ROUND 12 — C_w=64 remap, UNIFORM WAVE SHAPE. r1/r11 proved the remap's
// data-side effect (conflicts 5.4M -> 3.3M, both attempts) but both spilled:
// the divergent if/else with two inlined template bodies defeats the register
// allocator (r11: VGPR 88 + 8.5MB scratch despite a 256-reg budget). Fix:
// BMR 80 -> 96 so 8 waves = 4 col-groups x 2 row-groups of EXACTLY 3 row
// tiles (48 rows) each — one code path, no divergence. Register need:
// acc 48 + B-depth-3 48 + gr 16 + af 12 + addr ~25 = ~150 <= 256
// (__launch_bounds__(512,2): 2 waves/SIMD min = our exact occupancy).
// Per-slab per-CU: af-LDS 2400 -> 1200 cyc (each row read by 4 waves not 8),
// conflicts -400, B-via-L1 +1250 (same-address second read = L1 hit).
// TRIPWIRES: VGPR >= 130 and WRITE_SIZE ~1MB, else allocator-blocked -> r10.
// Retained from r10: staggered staging (gather-read at kt under that kt's
// MFMAs, write at kt+1; lgkm in-order makes both free), 16B table entries
// (single b128 gather), compute-first ordering, lgkm-only barrier, x
// prefetched a slab ahead, fused head with relaxed device-scope sync.
__global__ __launch_bounds__(512, 2) void gemm_kernel(const int* __restrict__ x,
                                                      const float* __restrict__ emb,
                                                      const unsigned short* __restrict__ Wtf,
                                                      const float* __restrict__ b1,
                                                      const float* __restrict__ b2,
                                                      float* __restrict__ pool,
                                                      int* __restrict__ cnt,
                                                      const float* __restrict__ wd1,
                                                      const float* __restrict__ bd1,
                                                      const float* __restrict__ wd2,
                                                      const float* __restrict__ bd2,
                                                      float* __restrict__ out) {
    __shared__ __align__(16) unsigned short tableL[VOCAB * 8];   // 4112 B
    __shared__ __align__(16) unsigned short As[2][BMR * AROWSH]; // 2 x 31.5 KB

    const int tid  = threadIdx.x;
    const int lane = tid & 63;
    const int wv   = tid >> 6;                         // 0..7
    const int m0   = blockIdx.x * BMR;
    const int r16  = lane & 15;
    const int q    = lane >> 4;                        // 0..3
    const int cg   = wv & 3;                           // col-group 0..3
    const int rg   = wv >> 2;                          // row-group 0..1 (48 rows each)

    // ---- build bf16 emb table in LDS (16B entries) ----
    if (tid < VOCAB) {
        const float4* er = (const float4*)(emb + tid * 8);
        float4 a = er[0], b = er[1];
        uint4 u;
        u.x = pack2(a.x, a.y); u.y = pack2(a.z, a.w);
        u.z = pack2(b.x, b.y); u.w = pack2(b.z, b.w);
        *(uint4*)(tableL + tid * 8) = u;
    }

    // ---- staging roles: thread handles idx = tid + 512*l (idx < 1920) ----
    const int* xptr[4];
    int        loff[4];
    bool       sval[4];
    bool       sact[4];
#pragma unroll
    for (int l = 0; l < 4; ++l) {
        sact[l] = (l < 3) || (tid < STAGEN - 3 * 512);  // slot 3: tids 0..383
        int idx = tid + 512 * l;
        sval[l] = (idx < STAGEN);
        int ic  = sval[l] ? idx : 0;
        int row = ic / SLABP;
        int pos = ic - row * SLABP;
        int am  = m0 + row;
        bool av = sval[l] && (am < MROWS);
        sval[l] = av;
        int amc = av ? am : 0;
        int b   = amc / TWIN;
        int t   = amc - b * TWIN;
        xptr[l] = x + ((size_t)b * LSEQ + (size_t)t * KCONV + pos);
        loff[l] = row * AROWSH + pos * 8;
    }

    // ---- compute role: two owned columns, both gate halves ----
    const int o0 = cg * 32 + r16;
    const int o1 = o0 + 16;
    const size_t boff[4] = {
        (size_t)o0 * 32 + q * 8,
        (size_t)(o0 + 128) * 32 + q * 8,
        (size_t)o1 * 32 + q * 8,
        (size_t)(o1 + 128) * 32 + q * 8
    };
    const int rbase = rg * 3;                          // first of 3 row tiles

    floatx4 acc[3][4];
#pragma unroll
    for (int i = 0; i < 3; ++i)
#pragma unroll
        for (int j = 0; j < 4; ++j) acc[i][j] = floatx4{0, 0, 0, 0};

    // ---- x values for slab 0 ----
    int xv[4], xn[4];
#pragma unroll
    for (int l = 0; l < 4; ++l) xv[l] = sval[l] ? xptr[l][0] : VOCABP;
    __syncthreads();                                   // table visible

    // ---- stage slab 0 into buf 0 (unavoidable burst before first compute) ----
#pragma unroll
    for (int l = 0; l < 4; ++l) {
        if (sact[l]) {
            uint4 g = *(const uint4*)(tableL + xv[l] * 8);
            *(uint4*)((unsigned short*)As + loff[l]) = g;
        }
    }
#pragma unroll
    for (int l = 0; l < 4; ++l) xv[l] = sval[l] ? xptr[l][SLABP] : VOCABP;
    LDS_BARRIER();

    // ---- B prefetch prologue: g=0,1 (4 frags x 2 stages) ----
    bf16x8 bc0[4], bc1[4], bc2[4] = {};
#pragma unroll
    for (int j = 0; j < 4; ++j) {
        bc0[j] = *(const bf16x8*)(Wtf + boff[j]);
        bc1[j] = *(const bf16x8*)(Wtf + PLANE + boff[j]);
    }

    int buf = 0;
    for (int s = 0; s < NSLAB; ++s) {
        if (s + 2 < NSLAB) {
#pragma unroll
            for (int l = 0; l < 4; ++l)
                xn[l] = sval[l] ? xptr[l][(s + 2) * SLABP] : VOCABP;
        }

        const unsigned short* Asb  = (const unsigned short*)As + buf * (BMR * AROWSH);
        unsigned short*       dstS = (unsigned short*)As + (buf ^ 1) * (BMR * AROWSH);
        const bool stg = (s + 1 < NSLAB);
        uint4 gr[4];

        // ---- 5 BK=32 iterations; B depth-3 pipeline; staggered staging ----
#pragma unroll
        for (int kt = 0; kt < 5; ++kt) {
            const int g = s * 5 + kt;
            if (g + 2 < NG) {
                const unsigned short* Wp = Wtf + (size_t)(g + 2) * PLANE;
#pragma unroll
                for (int j = 0; j < 4; ++j)
                    bc2[j] = *(const bf16x8*)(Wp + boff[j]);
            }
            bf16x8 af[3];
#pragma unroll
            for (int i = 0; i < 3; ++i)
                af[i] = *(const bf16x8*)(Asb + ((rbase + i) * 16 + r16) * AROWSH
                                         + (kt * 4 + q) * 8);

            // gather-READ slot kt: single b128; issued with this kt's af reads
            if (kt < 4 && stg && sact[kt])
                gr[kt] = *(const uint4*)(tableL + xv[kt] * 8);

#pragma unroll
            for (int i = 0; i < 3; ++i) {
#pragma unroll
                for (int j = 0; j < 4; ++j)
                    acc[i][j] = __builtin_amdgcn_mfma_f32_16x16x32_bf16(
                        af[i], bc0[j], acc[i][j], 0, 0, 0);
            }
#pragma unroll
            for (int j = 0; j < 4; ++j) { bc0[j] = bc1[j]; bc1[j] = bc2[j]; }

            // gather-WRITE slot kt-1: data arrived a full kt ago -> no stall
            if (kt >= 1 && stg && sact[kt - 1])
                *(uint4*)(dstS + loff[kt - 1]) = gr[kt - 1];
        }
#pragma unroll
        for (int l = 0; l < 4; ++l) xv[l] = xn[l];
        LDS_BARRIER();
        buf ^= 1;
    }

    // ---- epilogue: gate + per-batch max, two columns per lane ----
    // C/D layout: col = lane&15 (n), row = q*4 + reg (m).
    const float b10 = b1[o0], b20 = b2[o0];
    const float b11 = b1[o1], b21 = b2[o1];
    float cur0 = 0.0f, cur1 = 0.0f;
    int curb = (m0 + rbase * 16 + q * 4) / TWIN;
#pragma unroll
    for (int i = 0; i < 3; ++i) {
#pragma unroll
        for (int rgi = 0; rgi < 4; ++rgi) {
            const int row = m0 + (rbase + i) * 16 + q * 4 + rgi;
            if (row < MROWS) {
                const int bb = row / TWIN;
                if (bb != curb) {
                    atomicMax((int*)&pool[curb * COUT + o0], __float_as_int(cur0));
                    atomicMax((int*)&pool[curb * COUT + o1], __float_as_int(cur1));
                    cur0 = 0.0f; cur1 = 0.0f; curb = bb;
                }
                {
                    const float c1 = acc[i][0][rgi] + b10;
                    const float c2 = acc[i][1][rgi] + b20;
                    cur0 = fmaxf(cur0, fmaxf(c1, 0.0f) / (1.0f + __expf(-c2)));
                }
                {
                    const float c1 = acc[i][2][rgi] + b11;
                    const float c2 = acc[i][3][rgi] + b21;
                    cur1 = fmaxf(cur1, fmaxf(c1, 0.0f) / (1.0f + __expf(-c2)));
                }
            }
        }
    }
    atomicMax((int*)&pool[curb * COUT + o0], __float_as_int(cur0));
    atomicMax((int*)&pool[curb * COUT + o1], __float_as_int(cur1));

    // ---- fused head: last block to finish does the dense layers ----
    asm volatile("s_waitcnt vmcnt(0)" ::: "memory");
    __syncthreads();
    __shared__ int lastFlag;
    if (tid == 0) {
        int prev = __hip_atomic_fetch_add(cnt, 1, __ATOMIC_RELAXED, __HIP_MEMORY_SCOPE_AGENT);
        lastFlag = (prev == NTILE - 1) ? 1 : 0;
    }
    __syncthreads();
    if (!lastFlag) return;

    // reuse As as scratch: poolL[1024] + red[8][128]
    float* poolL = (float*)As;
    float* red   = poolL + BATCH * COUT;
    poolL[tid] = __int_as_float(
        __hip_atomic_load((int*)&pool[tid], __ATOMIC_RELAXED, __HIP_MEMORY_SCOPE_AGENT));
    poolL[tid + 512] = __int_as_float(
        __hip_atomic_load((int*)&pool[tid + 512], __ATOMIC_RELAXED, __HIP_MEMORY_SCOPE_AGENT));
    __syncthreads();

    if (tid < COUT) {
        const int j = tid;
        const float wj = wd2[j];
#pragma unroll
        for (int b = 0; b < BATCH; ++b) {
            float s = bd1[j];
            for (int i = 0; i < COUT; ++i) s += poolL[b * COUT + i] * wd1[j * COUT + i];
            red[b * COUT + j] = fmaxf(s, 0.0f) * wj;
        }
    }
    __syncthreads();
    if (tid < BATCH) {
        float s = 0.0f;
        for (int i = 0; i < COUT; ++i) s += red[tid * COUT + i];
        out[tid] = 1.0f / (1.0f + expf(-(s + bd2[0])));
    }
}

// ---------------- launch ----------------
extern "C" void kernel_launch(void* const* d_in, const int* in_sizes, int n_in,
                              void* d_out, int out_size, void* d_ws, size_t ws_size,
                              hipStream_t stream) {
    const int*   x   = (const int*)d_in[0];
    const float* emb = (const float*)d_in[1];
    const float* w1  = (const float*)d_in[2];
    const float* b1  = (const float*)d_in[3];
    const float* w2  = (const float*)d_in[4];
    const float* b2  = (const float*)d_in[5];
    const float* wd1 = (const float*)d_in[6];
    const float* bd1 = (const float*)d_in[7];
    const float* wd2 = (const float*)d_in[8];
    const float* bd2 = (const float*)d_in[9];
    float* out = (float*)d_out;

    unsigned short* Wtf  = (unsigned short*)((char*)d_ws + WTF_OFF);
    float*          pool = (float*)((char*)d_ws + POOL_OFF);
    int*            cnt  = (int*)((char*)d_ws + CNT_OFF);

    wprep_kernel<<<dim3(NDIM), dim3(256), 0, stream>>>(w1, w2, Wtf, pool, cnt);
    gemm_kernel<<<dim3(NTILE), dim3(512), 0, stream>>>(x, emb, Wtf, b1, b2, pool, cnt,
                                                       wd1, bd1, wd2, bd2, out);
}

// Round 13
// 166.634 us; speedup vs baseline: 1.3441x; 1.3441x over previous
//
#include <hip/hip_runtime.h>

// ---------------- problem constants ----------------
#define BATCH   8
#define LSEQ    1048576          // 1<<20
#define KCONV   500
#define TWIN    2097             // (L-K)/K + 1
#define MROWS   16776            // BATCH*TWIN
#define KDIM    4000             // KCONV * C_IN
#define NDIM    256              // 2 * C_OUT
#define COUT    128
#define VOCAB   257
#define VOCABP  256              // padding row of emb (zeros)

#define BMR     80               // m-rows per block (5 x 16)
#define NTILE   210              // ceil(MROWS/80): fits 256 CUs, 1 block/CU
#define SLABP   20               // positions per slab = 160 k = 5 BK32 iters
#define NSLAB   25
#define NG      125              // total BK32 iterations
#define PLANE   (NDIM * 32)      // 8192 shorts per g-plane of Wtf
#define AROWSH  168              // padded shorts per A-slab row (160 + 8)
#define STAGEN  (BMR * SLABP)    // 1600 gathers per slab

// ---------------- ws layout (bytes) ----------------
#define WTF_OFF   0ull
#define WTF_BYTES ((size_t)NG * PLANE * 2)                  // 2,048,000
#define POOL_OFF  (WTF_OFF + WTF_BYTES)                     // 1024 floats
#define CNT_OFF   (POOL_OFF + 4096)                         // 1 int

typedef __attribute__((ext_vector_type(8))) __bf16 bf16x8;
typedef __attribute__((ext_vector_type(4))) float  floatx4;

__device__ inline unsigned short f2bf(float f) {
    union { float f; unsigned u; } c; c.f = f;
    return (unsigned short)((c.u + 0x7FFFu + ((c.u >> 16) & 1u)) >> 16);
}
__device__ inline unsigned pack2(float lo, float hi) {
    return (unsigned)f2bf(lo) | ((unsigned)f2bf(hi) << 16);
}

// barrier that waits ONLY for LDS ops — leaves global (B/x prefetch) loads in flight
#define LDS_BARRIER() asm volatile("s_waitcnt lgkmcnt(0)\n\ts_barrier" ::: "memory")

// ---------------- kernel 1: frag-major weights + zero pool/counter ----------------
// Wtf[g][n][kk] = w_n[e=(g*32+kk)&7][p=(g*32+kk)>>3]
__global__ __launch_bounds__(256) void wprep_kernel(const float* __restrict__ w1,
                                                    const float* __restrict__ w2,
                                                    unsigned short* __restrict__ Wtf,
                                                    float* __restrict__ pool,
                                                    int* __restrict__ cnt) {
    const int n   = blockIdx.x;                        // 0..255
    const int tid = threadIdx.x;
    __shared__ float tile[KDIM];                       // 16 KB
    const float* src = (n < COUT) ? (w1 + (size_t)n * KDIM)
                                  : (w2 + (size_t)(n - COUT) * KDIM);
    for (int i = tid; i < KDIM; i += 256) tile[i] = src[i];
    __syncthreads();
    for (int i = tid; i < KDIM; i += 256) {
        int g = i >> 5, kk = i & 31;
        Wtf[(size_t)g * PLANE + n * 32 + kk] = f2bf(tile[(i & 7) * KCONV + (i >> 3)]);
    }
    if (n == 0) {
        if (tid < 256) ((float4*)pool)[tid] = float4{0.f, 0.f, 0.f, 0.f};
        if (tid == 0) *cnt = 0;
    }
}

// ---------------- kernel 2: fused embed + full-K GEMM + gate + max-pool + head ----------------
// ROUND 13 — r10 base (best verified, 159.4us total) + CRITICAL-PATH-ONLY af
// PREFETCH. The C_w=64 remap is abandoned: three attempts (r1/r11/r12) all
// validated its data effect (conflicts 5.4M -> 3.3M) but the allocator pins
// VGPR at ~84-88 and spills the 4-wide B pipeline (WRITE_SIZE ~8MB) in every
// code shape tried, including uniform waves + __launch_bounds__(512,2).
// Remaining accounted stall: each kt's first MFMA waits ~120cy on its own
// af[0] ds_read_b128 (125 kts, ~60-80cy exposed at 2 waves/SIMD). r9 fixed
// this with a full af rotation (+80 regs -> spill). Minimal form here:
// prefetch ONLY af[0] one kt ahead (+8-16 regs on r10's 68, below the ~88
// spill wall). kt0 of each slab keeps its wait (next-slab buffer is still
// being written at kt=4 — cross-buffer prefetch would race).
// TRIPWIRE: WRITE_SIZE ~1MB, VGPR <= 84. If spilled -> exact r10 is final.
// Retained from r10: staggered staging (gather-read at kt under that kt's
// MFMAs, write at kt+1; lgkm in-order makes both free), 16B table entries
// (single b128 gather), compute-first ordering, lgkm-only barrier, x
// prefetched a slab ahead on vmcnt, fused head with relaxed device-scope
// sync (no cache-maintenance fences — the r3 variant cost ~45us).
__global__ __launch_bounds__(512) void gemm_kernel(const int* __restrict__ x,
                                                   const float* __restrict__ emb,
                                                   const unsigned short* __restrict__ Wtf,
                                                   const float* __restrict__ b1,
                                                   const float* __restrict__ b2,
                                                   float* __restrict__ pool,
                                                   int* __restrict__ cnt,
                                                   const float* __restrict__ wd1,
                                                   const float* __restrict__ bd1,
                                                   const float* __restrict__ wd2,
                                                   const float* __restrict__ bd2,
                                                   float* __restrict__ out) {
    __shared__ __align__(16) unsigned short tableL[VOCAB * 8];   // 4112 B
    __shared__ __align__(16) unsigned short As[2][BMR * AROWSH]; // 2 x 26.25 KB

    const int tid  = threadIdx.x;
    const int lane = tid & 63;
    const int wv   = tid >> 6;                         // 0..7
    const int m0   = blockIdx.x * BMR;
    const int r16  = lane & 15;
    const int q    = lane >> 4;                        // 0..3

    // ---- build bf16 emb table in LDS (16B entries) ----
    if (tid < VOCAB) {
        const float4* er = (const float4*)(emb + tid * 8);
        float4 a = er[0], b = er[1];
        uint4 u;
        u.x = pack2(a.x, a.y); u.y = pack2(a.z, a.w);
        u.z = pack2(b.x, b.y); u.w = pack2(b.z, b.w);
        *(uint4*)(tableL + tid * 8) = u;
    }

    // ---- staging roles: thread handles idx = tid + 512*l (idx < 1600) ----
    const int* xptr[4];
    int        loff[4];
    bool       sval[4];
    bool       sact[4];
#pragma unroll
    for (int l = 0; l < 4; ++l) {
        sact[l] = (l < 3) || (tid < STAGEN - 3 * 512);  // slot 3: tids 0..63 only
        int idx = tid + 512 * l;
        sval[l] = (idx < STAGEN);
        int ic  = sval[l] ? idx : 0;
        int row = ic / SLABP;
        int pos = ic - row * SLABP;
        int am  = m0 + row;
        bool av = sval[l] && (am < MROWS);
        sval[l] = av;
        int amc = av ? am : 0;
        int b   = amc / TWIN;
        int t   = amc - b * TWIN;
        xptr[l] = x + ((size_t)b * LSEQ + (size_t)t * KCONV + pos);
        loff[l] = row * AROWSH + pos * 8;
    }

    // ---- compute role ----
    const int o = wv * 16 + r16;                       // 0..127
    const size_t boff0 = (size_t)o * 32 + q * 8;
    const size_t boff1 = (size_t)(o + 128) * 32 + q * 8;

    floatx4 acc[5][2];
#pragma unroll
    for (int i = 0; i < 5; ++i) { acc[i][0] = floatx4{0,0,0,0}; acc[i][1] = floatx4{0,0,0,0}; }

    // ---- x values for slab 0 ----
    int xv[4], xn[4];
#pragma unroll
    for (int l = 0; l < 4; ++l) xv[l] = sval[l] ? xptr[l][0] : VOCABP;
    __syncthreads();                                   // table visible

    // ---- stage slab 0 into buf 0 (unavoidable burst before first compute) ----
#pragma unroll
    for (int l = 0; l < 4; ++l) {
        if (sact[l]) {
            uint4 g = *(const uint4*)(tableL + xv[l] * 8);
            *(uint4*)((unsigned short*)As + loff[l]) = g;
        }
    }
#pragma unroll
    for (int l = 0; l < 4; ++l) xv[l] = sval[l] ? xptr[l][SLABP] : VOCABP;
    LDS_BARRIER();

    // ---- B prefetch prologue: g=0,1 ----
    bf16x8 bc0[2], bc1[2], bc2[2] = {};
    bc0[0] = *(const bf16x8*)(Wtf + boff0);
    bc0[1] = *(const bf16x8*)(Wtf + boff1);
    bc1[0] = *(const bf16x8*)(Wtf + PLANE + boff0);
    bc1[1] = *(const bf16x8*)(Wtf + PLANE + boff1);

    int buf = 0;
    for (int s = 0; s < NSLAB; ++s) {
        // issue x loads for slab s+2 early (vmcnt; a full slab of cover)
        if (s + 2 < NSLAB) {
#pragma unroll
            for (int l = 0; l < 4; ++l)
                xn[l] = sval[l] ? xptr[l][(s + 2) * SLABP] : VOCABP;
        }

        const unsigned short* Asb  = (const unsigned short*)As + buf * (BMR * AROWSH);
        unsigned short*       dstS = (unsigned short*)As + (buf ^ 1) * (BMR * AROWSH);
        const bool stg = (s + 1 < NSLAB);
        uint4 gr[4];

        // af[0] for kt=0: issued immediately after the barrier (same wait as
        // before, just earlier in the instruction stream)
        bf16x8 af0c = *(const bf16x8*)(Asb + r16 * AROWSH + q * 8);

        // ---- 5 BK=32 iterations; B depth-2 pipeline; staged gathers ----
#pragma unroll
        for (int kt = 0; kt < 5; ++kt) {
            const int g = s * 5 + kt;
            if (g + 2 < NG) {
                const unsigned short* Wp = Wtf + (size_t)(g + 2) * PLANE;
                bc2[0] = *(const bf16x8*)(Wp + boff0);
                bc2[1] = *(const bf16x8*)(Wp + boff1);
            }
            bf16x8 af[5];
            af[0] = af0c;                              // already in registers
#pragma unroll
            for (int i = 1; i < 5; ++i)
                af[i] = *(const bf16x8*)(Asb + (i * 16 + r16) * AROWSH + (kt * 4 + q) * 8);

            // prefetch af[0] for kt+1 (within this slab's buffer only)
            bf16x8 af0n = {};
            if (kt < 4)
                af0n = *(const bf16x8*)(Asb + r16 * AROWSH + ((kt + 1) * 4 + q) * 8);

            // gather-READ slot kt: single b128 from the 16B-stride table;
            // issued with this kt's af reads — the MFMA's counted lgkm wait
            // only covers af, leaving the gather outstanding.
            if (kt < 4 && stg && sact[kt])
                gr[kt] = *(const uint4*)(tableL + xv[kt] * 8);

#pragma unroll
            for (int i = 0; i < 5; ++i) {
                acc[i][0] = __builtin_amdgcn_mfma_f32_16x16x32_bf16(af[i], bc0[0], acc[i][0], 0, 0, 0);
                acc[i][1] = __builtin_amdgcn_mfma_f32_16x16x32_bf16(af[i], bc0[1], acc[i][1], 0, 0, 0);
            }
            bc0[0] = bc1[0]; bc0[1] = bc1[1];
            bc1[0] = bc2[0]; bc1[1] = bc2[1];

            // gather-WRITE slot kt-1: data arrived a full kt ago -> no stall;
            // kt's in-order lgkm traffic already drained the read.
            if (kt >= 1 && stg && sact[kt - 1])
                *(uint4*)(dstS + loff[kt - 1]) = gr[kt - 1];

            if (kt < 4) af0c = af0n;
        }
#pragma unroll
        for (int l = 0; l < 4; ++l) xv[l] = xn[l];
        LDS_BARRIER();
        buf ^= 1;
    }

    // ---- epilogue: gate + per-batch max in registers, atomicMax flush ----
    // C/D layout: col = lane&15 (n), row = q*4 + reg (m).
    const float b1v = b1[o], b2v = b2[o];
    float cur = 0.0f;
    int curb  = (m0 + q * 4) / TWIN;
#pragma unroll
    for (int i = 0; i < 5; ++i) {
#pragma unroll
        for (int rg = 0; rg < 4; ++rg) {
            const int row = m0 + i * 16 + q * 4 + rg;
            if (row < MROWS) {
                const int bb = row / TWIN;
                if (bb != curb) {
                    atomicMax((int*)&pool[curb * COUT + o], __float_as_int(cur));
                    cur = 0.0f; curb = bb;
                }
                const float c1 = acc[i][0][rg] + b1v;
                const float c2 = acc[i][1][rg] + b2v;
                const float g  = fmaxf(c1, 0.0f) / (1.0f + __expf(-c2));
                cur = fmaxf(cur, g);
            }
        }
    }
    atomicMax((int*)&pool[curb * COUT + o], __float_as_int(cur));

    // ---- fused head: last block to finish does the dense layers ----
    asm volatile("s_waitcnt vmcnt(0)" ::: "memory");
    __syncthreads();
    __shared__ int lastFlag;
    if (tid == 0) {
        int prev = __hip_atomic_fetch_add(cnt, 1, __ATOMIC_RELAXED, __HIP_MEMORY_SCOPE_AGENT);
        lastFlag = (prev == NTILE - 1) ? 1 : 0;
    }
    __syncthreads();
    if (!lastFlag) return;

    // reuse As as scratch: poolL[1024] + red[8][128]
    float* poolL = (float*)As;
    float* red   = poolL + BATCH * COUT;
    poolL[tid] = __int_as_float(
        __hip_atomic_load((int*)&pool[tid], __ATOMIC_RELAXED, __HIP_MEMORY_SCOPE_AGENT));
    poolL[tid + 512] = __int_as_float(
        __hip_atomic_load((int*)&pool[tid + 512], __ATOMIC_RELAXED, __HIP_MEMORY_SCOPE_AGENT));
    __syncthreads();

    if (tid < COUT) {
        const int j = tid;
        const float wj = wd2[j];
#pragma unroll
        for (int b = 0; b < BATCH; ++b) {
            float s = bd1[j];
            for (int i = 0; i < COUT; ++i) s += poolL[b * COUT + i] * wd1[j * COUT + i];
            red[b * COUT + j] = fmaxf(s, 0.0f) * wj;
        }
    }
    __syncthreads();
    if (tid < BATCH) {
        float s = 0.0f;
        for (int i = 0; i < COUT; ++i) s += red[tid * COUT + i];
        out[tid] = 1.0f / (1.0f + expf(-(s + bd2[0])));
    }
}

// ---------------- launch ----------------
extern "C" void kernel_launch(void* const* d_in, const int* in_sizes, int n_in,
                              void* d_out, int out_size, void* d_ws, size_t ws_size,
                              hipStream_t stream) {
    const int*   x   = (const int*)d_in[0];
    const float* emb = (const float*)d_in[1];
    const float* w1  = (const float*)d_in[2];
    const float* b1  = (const float*)d_in[3];
    const float* w2  = (const float*)d_in[4];
    const float* b2  = (const float*)d_in[5];
    const float* wd1 = (const float*)d_in[6];
    const float* bd1 = (const float*)d_in[7];
    const float* wd2 = (const float*)d_in[8];
    const float* bd2 = (const float*)d_in[9];
    float* out = (float*)d_out;

    unsigned short* Wtf  = (unsigned short*)((char*)d_ws + WTF_OFF);
    float*          pool = (float*)((char*)d_ws + POOL_OFF);
    int*            cnt  = (int*)((char*)d_ws + CNT_OFF);

    wprep_kernel<<<dim3(NDIM), dim3(256), 0, stream>>>(w1, w2, Wtf, pool, cnt);
    gemm_kernel<<<dim3(NTILE), dim3(512), 0, stream>>>(x, emb, Wtf, b1, b2, pool, cnt,
                                                       wd1, bd1, wd2, bd2, out);
}

// Round 14
// 158.960 us; speedup vs baseline: 1.4090x; 1.0483x over previous
//
#include <hip/hip_runtime.h>

// ---------------- problem constants ----------------
#define BATCH   8
#define LSEQ    1048576          // 1<<20
#define KCONV   500
#define TWIN    2097             // (L-K)/K + 1
#define MROWS   16776            // BATCH*TWIN
#define KDIM    4000             // KCONV * C_IN
#define NDIM    256              // 2 * C_OUT
#define COUT    128
#define VOCAB   257
#define VOCABP  256              // padding row of emb (zeros)

#define BMR     80               // m-rows per block (5 x 16)
#define NTILE   210              // ceil(MROWS/80): fits 256 CUs, 1 block/CU
#define SLABP   20               // positions per slab = 160 k = 5 BK32 iters
#define NSLAB   25
#define NG      125              // total BK32 iterations
#define PLANE   (NDIM * 32)      // 8192 shorts per g-plane of Wtf
#define AROWSH  168              // padded shorts per A-slab row (160 + 8)
#define STAGEN  (BMR * SLABP)    // 1600 gathers per slab

// ---------------- ws layout (bytes) ----------------
#define WTF_OFF   0ull
#define WTF_BYTES ((size_t)NG * PLANE * 2)                  // 2,048,000
#define POOL_OFF  (WTF_OFF + WTF_BYTES)                     // 1024 floats
#define CNT_OFF   (POOL_OFF + 4096)                         // 1 int

typedef __attribute__((ext_vector_type(8))) __bf16 bf16x8;
typedef __attribute__((ext_vector_type(4))) float  floatx4;

__device__ inline unsigned short f2bf(float f) {
    union { float f; unsigned u; } c; c.f = f;
    return (unsigned short)((c.u + 0x7FFFu + ((c.u >> 16) & 1u)) >> 16);
}
__device__ inline unsigned pack2(float lo, float hi) {
    return (unsigned)f2bf(lo) | ((unsigned)f2bf(hi) << 16);
}

// barrier that waits ONLY for LDS ops — leaves global (B/x prefetch) loads in flight
#define LDS_BARRIER() asm volatile("s_waitcnt lgkmcnt(0)\n\ts_barrier" ::: "memory")

// ---------------- kernel 1: frag-major weights + zero pool/counter ----------------
// Wtf[g][n][kk] = w_n[e=(g*32+kk)&7][p=(g*32+kk)>>3]
__global__ __launch_bounds__(256) void wprep_kernel(const float* __restrict__ w1,
                                                    const float* __restrict__ w2,
                                                    unsigned short* __restrict__ Wtf,
                                                    float* __restrict__ pool,
                                                    int* __restrict__ cnt) {
    const int n   = blockIdx.x;                        // 0..255
    const int tid = threadIdx.x;
    __shared__ float tile[KDIM];                       // 16 KB
    const float* src = (n < COUT) ? (w1 + (size_t)n * KDIM)
                                  : (w2 + (size_t)(n - COUT) * KDIM);
    for (int i = tid; i < KDIM; i += 256) tile[i] = src[i];
    __syncthreads();
    for (int i = tid; i < KDIM; i += 256) {
        int g = i >> 5, kk = i & 31;
        Wtf[(size_t)g * PLANE + n * 32 + kk] = f2bf(tile[(i & 7) * KCONV + (i >> 3)]);
    }
    if (n == 0) {
        if (tid < 256) ((float4*)pool)[tid] = float4{0.f, 0.f, 0.f, 0.f};
        if (tid == 0) *cnt = 0;
    }
}

// ---------------- kernel 2: fused embed + full-K GEMM + gate + max-pool + head ----------------
// FINAL (r10 configuration — best verified, 159.4us total; r13's af[0]
// prefetch was neutral-negative and is reverted).
// Structure ledger (14 rounds of counter evidence):
//  * staggered staging: gather-read at kt=l issued under that kt's MFMAs,
//    gather-write at kt=l+1 (lgkm in-order -> both free). +8us vs burst.
//  * 16B table entries: single ds_read_b128 gather (36B stride RAISED
//    conflicts 5.4M->6.7M; 16B is optimal given the allocator blocks C_w=64).
//  * compute-first ordering + lgkm-only barrier: B/x global prefetches stay
//    in flight across slab boundaries; staging drains into the barrier.
//  * fused head with RELAXED device-scope sync: atomicMax is device-scope on
//    CDNA; vmcnt(0) + __syncthreads + relaxed agent fetch_add. (threadfence/
//    ACQ_REL variant cost ~45us in per-block L2 writebacks; cooperative
//    grid.sync cost ~25us in-kernel +35us runtime.)
//  * 1 block/CU, 8 waves, BMR=80: 2+ blocks/CU oversubscribes the LDS pipe
//    (-50us); slab-size is neutral; C_w=64 remap halves af traffic
//    (conflicts 3.3M, verified 3x) but the register allocator pins ~84-88
//    VGPR and spills 8MB scratch in every code shape tried -> unreachable.
// Remaining gap to the 20us MFMA floor is latency/serialization at 2
// waves/SIMD that no source-level edit reached; ~78us of total is fixed
// harness/launch overhead (proven minimal at 2 launches).
__global__ __launch_bounds__(512) void gemm_kernel(const int* __restrict__ x,
                                                   const float* __restrict__ emb,
                                                   const unsigned short* __restrict__ Wtf,
                                                   const float* __restrict__ b1,
                                                   const float* __restrict__ b2,
                                                   float* __restrict__ pool,
                                                   int* __restrict__ cnt,
                                                   const float* __restrict__ wd1,
                                                   const float* __restrict__ bd1,
                                                   const float* __restrict__ wd2,
                                                   const float* __restrict__ bd2,
                                                   float* __restrict__ out) {
    __shared__ __align__(16) unsigned short tableL[VOCAB * 8];   // 4112 B
    __shared__ __align__(16) unsigned short As[2][BMR * AROWSH]; // 2 x 26.25 KB

    const int tid  = threadIdx.x;
    const int lane = tid & 63;
    const int wv   = tid >> 6;                         // 0..7
    const int m0   = blockIdx.x * BMR;
    const int r16  = lane & 15;
    const int q    = lane >> 4;                        // 0..3

    // ---- build bf16 emb table in LDS (16B entries) ----
    if (tid < VOCAB) {
        const float4* er = (const float4*)(emb + tid * 8);
        float4 a = er[0], b = er[1];
        uint4 u;
        u.x = pack2(a.x, a.y); u.y = pack2(a.z, a.w);
        u.z = pack2(b.x, b.y); u.w = pack2(b.z, b.w);
        *(uint4*)(tableL + tid * 8) = u;
    }

    // ---- staging roles: thread handles idx = tid + 512*l (idx < 1600) ----
    const int* xptr[4];
    int        loff[4];
    bool       sval[4];
    bool       sact[4];
#pragma unroll
    for (int l = 0; l < 4; ++l) {
        sact[l] = (l < 3) || (tid < STAGEN - 3 * 512);  // slot 3: tids 0..63 only
        int idx = tid + 512 * l;
        sval[l] = (idx < STAGEN);
        int ic  = sval[l] ? idx : 0;
        int row = ic / SLABP;
        int pos = ic - row * SLABP;
        int am  = m0 + row;
        bool av = sval[l] && (am < MROWS);
        sval[l] = av;
        int amc = av ? am : 0;
        int b   = amc / TWIN;
        int t   = amc - b * TWIN;
        xptr[l] = x + ((size_t)b * LSEQ + (size_t)t * KCONV + pos);
        loff[l] = row * AROWSH + pos * 8;
    }

    // ---- compute role ----
    const int o = wv * 16 + r16;                       // 0..127
    const size_t boff0 = (size_t)o * 32 + q * 8;
    const size_t boff1 = (size_t)(o + 128) * 32 + q * 8;

    floatx4 acc[5][2];
#pragma unroll
    for (int i = 0; i < 5; ++i) { acc[i][0] = floatx4{0,0,0,0}; acc[i][1] = floatx4{0,0,0,0}; }

    // ---- x values for slab 0 ----
    int xv[4], xn[4];
#pragma unroll
    for (int l = 0; l < 4; ++l) xv[l] = sval[l] ? xptr[l][0] : VOCABP;
    __syncthreads();                                   // table visible

    // ---- stage slab 0 into buf 0 (unavoidable burst before first compute) ----
#pragma unroll
    for (int l = 0; l < 4; ++l) {
        if (sact[l]) {
            uint4 g = *(const uint4*)(tableL + xv[l] * 8);
            *(uint4*)((unsigned short*)As + loff[l]) = g;
        }
    }
#pragma unroll
    for (int l = 0; l < 4; ++l) xv[l] = sval[l] ? xptr[l][SLABP] : VOCABP;
    LDS_BARRIER();

    // ---- B prefetch prologue: g=0,1 ----
    bf16x8 bc0[2], bc1[2], bc2[2] = {};
    bc0[0] = *(const bf16x8*)(Wtf + boff0);
    bc0[1] = *(const bf16x8*)(Wtf + boff1);
    bc1[0] = *(const bf16x8*)(Wtf + PLANE + boff0);
    bc1[1] = *(const bf16x8*)(Wtf + PLANE + boff1);

    int buf = 0;
    for (int s = 0; s < NSLAB; ++s) {
        // issue x loads for slab s+2 early (vmcnt; a full slab of cover)
        if (s + 2 < NSLAB) {
#pragma unroll
            for (int l = 0; l < 4; ++l)
                xn[l] = sval[l] ? xptr[l][(s + 2) * SLABP] : VOCABP;
        }

        const unsigned short* Asb  = (const unsigned short*)As + buf * (BMR * AROWSH);
        unsigned short*       dstS = (unsigned short*)As + (buf ^ 1) * (BMR * AROWSH);
        const bool stg = (s + 1 < NSLAB);
        uint4 gr[4];

        // ---- 5 BK=32 iterations; B depth-2 register pipeline; staged gathers ----
#pragma unroll
        for (int kt = 0; kt < 5; ++kt) {
            const int g = s * 5 + kt;
            if (g + 2 < NG) {
                const unsigned short* Wp = Wtf + (size_t)(g + 2) * PLANE;
                bc2[0] = *(const bf16x8*)(Wp + boff0);
                bc2[1] = *(const bf16x8*)(Wp + boff1);
            }
            bf16x8 af[5];
#pragma unroll
            for (int i = 0; i < 5; ++i)
                af[i] = *(const bf16x8*)(Asb + (i * 16 + r16) * AROWSH + (kt * 4 + q) * 8);

            // gather-READ slot kt: single b128 from the 16B-stride table;
            // issued with this kt's af reads — the MFMA's counted lgkm wait
            // only covers af, leaving the gather outstanding.
            if (kt < 4 && stg && sact[kt])
                gr[kt] = *(const uint4*)(tableL + xv[kt] * 8);

#pragma unroll
            for (int i = 0; i < 5; ++i) {
                acc[i][0] = __builtin_amdgcn_mfma_f32_16x16x32_bf16(af[i], bc0[0], acc[i][0], 0, 0, 0);
                acc[i][1] = __builtin_amdgcn_mfma_f32_16x16x32_bf16(af[i], bc0[1], acc[i][1], 0, 0, 0);
            }
            bc0[0] = bc1[0]; bc0[1] = bc1[1];
            bc1[0] = bc2[0]; bc1[1] = bc2[1];

            // gather-WRITE slot kt-1: data arrived a full kt ago -> no stall;
            // kt's in-order lgkm traffic already drained the read.
            if (kt >= 1 && stg && sact[kt - 1])
                *(uint4*)(dstS + loff[kt - 1]) = gr[kt - 1];
        }
#pragma unroll
        for (int l = 0; l < 4; ++l) xv[l] = xn[l];
        LDS_BARRIER();
        buf ^= 1;
    }

    // ---- epilogue: gate + per-batch max in registers, atomicMax flush ----
    // C/D layout: col = lane&15 (n), row = q*4 + reg (m).
    const float b1v = b1[o], b2v = b2[o];
    float cur = 0.0f;
    int curb  = (m0 + q * 4) / TWIN;
#pragma unroll
    for (int i = 0; i < 5; ++i) {
#pragma unroll
        for (int rg = 0; rg < 4; ++rg) {
            const int row = m0 + i * 16 + q * 4 + rg;
            if (row < MROWS) {
                const int bb = row / TWIN;
                if (bb != curb) {
                    atomicMax((int*)&pool[curb * COUT + o], __float_as_int(cur));
                    cur = 0.0f; curb = bb;
                }
                const float c1 = acc[i][0][rg] + b1v;
                const float c2 = acc[i][1][rg] + b2v;
                const float g  = fmaxf(c1, 0.0f) / (1.0f + __expf(-c2));
                cur = fmaxf(cur, g);
            }
        }
    }
    atomicMax((int*)&pool[curb * COUT + o], __float_as_int(cur));

    // ---- fused head: last block to finish does the dense layers ----
    asm volatile("s_waitcnt vmcnt(0)" ::: "memory");
    __syncthreads();
    __shared__ int lastFlag;
    if (tid == 0) {
        int prev = __hip_atomic_fetch_add(cnt, 1, __ATOMIC_RELAXED, __HIP_MEMORY_SCOPE_AGENT);
        lastFlag = (prev == NTILE - 1) ? 1 : 0;
    }
    __syncthreads();
    if (!lastFlag) return;

    // reuse As as scratch: poolL[1024] + red[8][128]
    float* poolL = (float*)As;
    float* red   = poolL + BATCH * COUT;
    poolL[tid] = __int_as_float(
        __hip_atomic_load((int*)&pool[tid], __ATOMIC_RELAXED, __HIP_MEMORY_SCOPE_AGENT));
    poolL[tid + 512] = __int_as_float(
        __hip_atomic_load((int*)&pool[tid + 512], __ATOMIC_RELAXED, __HIP_MEMORY_SCOPE_AGENT));
    __syncthreads();

    if (tid < COUT) {
        const int j = tid;
        const float wj = wd2[j];
#pragma unroll
        for (int b = 0; b < BATCH; ++b) {
            float s = bd1[j];
            for (int i = 0; i < COUT; ++i) s += poolL[b * COUT + i] * wd1[j * COUT + i];
            red[b * COUT + j] = fmaxf(s, 0.0f) * wj;
        }
    }
    __syncthreads();
    if (tid < BATCH) {
        float s = 0.0f;
        for (int i = 0; i < COUT; ++i) s += red[tid * COUT + i];
        out[tid] = 1.0f / (1.0f + expf(-(s + bd2[0])));
    }
}

// ---------------- launch ----------------
extern "C" void kernel_launch(void* const* d_in, const int* in_sizes, int n_in,
                              void* d_out, int out_size, void* d_ws, size_t ws_size,
                              hipStream_t stream) {
    const int*   x   = (const int*)d_in[0];
    const float* emb = (const float*)d_in[1];
    const float* w1  = (const float*)d_in[2];
    const float* b1  = (const float*)d_in[3];
    const float* w2  = (const float*)d_in[4];
    const float* b2  = (const float*)d_in[5];
    const float* wd1 = (const float*)d_in[6];
    const float* bd1 = (const float*)d_in[7];
    const float* wd2 = (const float*)d_in[8];
    const float* bd2 = (const float*)d_in[9];
    float* out = (float*)d_out;

    unsigned short* Wtf  = (unsigned short*)((char*)d_ws + WTF_OFF);
    float*          pool = (float*)((char*)d_ws + POOL_OFF);
    int*            cnt  = (int*)((char*)d_ws + CNT_OFF);

    wprep_kernel<<<dim3(NDIM), dim3(256), 0, stream>>>(w1, w2, Wtf, pool, cnt);
    gemm_kernel<<<dim3(NTILE), dim3(512), 0, stream>>>(x, emb, Wtf, b1, b2, pool, cnt,
                                                       wd1, bd1, wd2, bd2, out);
}